// Round 8
// baseline (92.638 us; speedup 1.0000x reference)
//
#include <hip/hip_runtime.h>
#include <hip/hip_bf16.h>

typedef __bf16 bf16_t;
typedef bf16_t bf16x2 __attribute__((ext_vector_type(2)));
typedef bf16_t bf16x4 __attribute__((ext_vector_type(4)));
typedef bf16_t bf16x8 __attribute__((ext_vector_type(8)));
typedef float  floatx4  __attribute__((ext_vector_type(4)));
typedef float  floatx16 __attribute__((ext_vector_type(16)));

constexpr int B = 8, N = 2048, D = 64;
constexpr int TSTR = 65;   // prepass transpose stride (fp32)

// --- prepass: 1-D grid, XCD-swizzled (b = bx&7 -> XCD b). z = bx>>8 selects K-convert / V-transpose ---
__global__ __launch_bounds__(256)
void prepass_kernel(const float* __restrict__ k, const float* __restrict__ v,
                    bf16_t* __restrict__ kb, bf16_t* __restrict__ vt) {
    __shared__ float t[64 * TSTR];
    const int tid = threadIdx.x;
    const int b   = blockIdx.x & 7;            // XCD-local batch
    const int r0  = ((blockIdx.x >> 3) & 31) * 64;
    if ((blockIdx.x >> 8) == 0) {
        const float* src = k + ((size_t)b * N + r0) * D;
        bf16_t* dst = kb + ((size_t)b * N + r0) * D;
        #pragma unroll
        for (int p = 0; p < 4; ++p) {
            int e = (tid + p * 256) * 4;
            floatx4 f = *(const floatx4*)(src + e);
            bf16x4 o;
            #pragma unroll
            for (int j = 0; j < 4; ++j) o[j] = (bf16_t)f[j];
            *(bf16x4*)(dst + e) = o;
        }
    } else {
        const float* vb = v + ((size_t)b * N + r0) * D;
        #pragma unroll
        for (int p = 0; p < 4; ++p) {
            int e = (tid + p * 256) * 4;
            int row = e >> 6, col = e & 63;
            floatx4 f = *(const floatx4*)(vb + e);
            #pragma unroll
            for (int j = 0; j < 4; ++j) t[(col + j) * TSTR + row] = f[j];
        }
        __syncthreads();
        bf16_t* ob = vt + (size_t)b * D * N + r0;
        #pragma unroll
        for (int p = 0; p < 4; ++p) {
            int e = (tid + p * 256) * 4;
            int drow = e >> 6, kcol = e & 63;
            bf16x4 o;
            #pragma unroll
            for (int j = 0; j < 4; ++j) o[j] = (bf16_t)t[drow * TSTR + kcol + j];
            *(bf16x4*)(ob + (size_t)drow * N + kcol) = o;
        }
    }
}

// --- flash attention, transposed (S^T = K Q^T, O^T = V^T P^T), BN=256, 8 waves ---
// 1-D grid of 512, b = bx&7: all 64 q-blocks of a batch land on one XCD
// (lin%8 heuristic) so K/V bf16 (512 KB/batch) stays resident in that XCD's L2.
__global__ __launch_bounds__(512, 4)
void attn_kernel(const float* __restrict__ q, const bf16_t* __restrict__ kb,
                 const bf16_t* __restrict__ vt, float* __restrict__ out) {
    __shared__ char smem[65536];
    bf16_t* lds_k = (bf16_t*)smem;              // [256][64] swizzled, 32 KB
    bf16_t* lds_v = (bf16_t*)(smem + 32768);    // [64][256] swizzled, 32 KB
    float*  o_buf = (float*)smem;               // post-loop overlay: [7][64][32]
    float*  l_buf = (float*)(smem + 57344);     // post-loop overlay: [7][32]

    const int tid  = threadIdx.x;
    const int lane = tid & 63;
    const int cg   = tid >> 6;     // wave = kv slice of 32 within the 256-tile
    const int h    = lane >> 5;    // half-wave
    const int l31  = lane & 31;
    const int sw   = l31 & 7;      // swizzle key for fragment reads

    const int b  = blockIdx.x & 7;             // XCD-local batch
    const int q0 = (blockIdx.x >> 3) * 32;

    const bf16_t* kbb = kb + (size_t)b * N * D;
    const bf16_t* vbb = vt + (size_t)b * D * N;

    // Q B-frags fp32->bf16: B[k=d][n=q=l31], k = h*8+j within each d-slice of 16
    bf16x8 qf[4];
    {
        const float* qp = q + ((size_t)b * N + q0 + l31) * D + h * 8;
        #pragma unroll
        for (int kd = 0; kd < 4; ++kd) {
            floatx4 f0 = *(const floatx4*)(qp + kd * 16);
            floatx4 f1 = *(const floatx4*)(qp + kd * 16 + 4);
            bf16x8 t;
            #pragma unroll
            for (int j = 0; j < 4; ++j) { t[j] = (bf16_t)f0[j]; t[j + 4] = (bf16_t)f1[j]; }
            qf[kd] = t;
        }
    }

    floatx16 o_acc[2];
    #pragma unroll
    for (int d = 0; d < 2; ++d)
        #pragma unroll
        for (int i = 0; i < 16; ++i) o_acc[d][i] = 0.f;
    float l_run = 0.f;

    // prefetch tile 0: K 256x64 contiguous; Vt rows (d) stride N
    bf16x8 kreg[4], vreg[4];
    #pragma unroll
    for (int p = 0; p < 4; ++p) {
        int e = (tid + p * 512) * 8;
        kreg[p] = *(const bf16x8*)(kbb + e);
        vreg[p] = *(const bf16x8*)(vbb + (size_t)(e >> 8) * N + (e & 255));
    }

    #pragma unroll 1
    for (int it = 0; it < N / 256; ++it) {
        __syncthreads();   // prev iter's frag reads done before overwrite
        #pragma unroll
        for (int p = 0; p < 4; ++p) {
            int e  = (tid + p * 512) * 8;
            int kr = e >> 6, kg = (e >> 3) & 7;
            *(bf16x8*)&lds_k[kr * 64 + ((kg ^ (kr & 7)) << 3)] = kreg[p];
            int vr = e >> 8, vg = (e >> 3) & 31;
            *(bf16x8*)&lds_v[vr * 256 + ((vg ^ (vr & 7)) << 3)] = vreg[p];
        }
        __syncthreads();
        if (it + 1 < N / 256) {
            const int kv1 = (it + 1) * 256;
            #pragma unroll
            for (int p = 0; p < 4; ++p) {
                int e = (tid + p * 512) * 8;
                kreg[p] = *(const bf16x8*)(kbb + (size_t)kv1 * D + e);
                vreg[p] = *(const bf16x8*)(vbb + (size_t)(e >> 8) * N + kv1 + (e & 255));
            }
        }

        // S^T = K Q^T (32kv x 32q)
        floatx16 s;
        #pragma unroll
        for (int i = 0; i < 16; ++i) s[i] = 0.f;
        #pragma unroll
        for (int kd = 0; kd < 4; ++kd) {
            bf16x8 kf = *(const bf16x8*)&lds_k[(cg * 32 + l31) * 64 + (((2 * kd + h) ^ sw) << 3)];
            s = __builtin_amdgcn_mfma_f32_32x32x16_bf16(kf, qf[kd], s, 0, 0, 0);
        }

        // scale + equality-mask (attn==0 -> -inf -> weight 0) + exp; pack bf16 pairs
        int q8[8];
        #pragma unroll
        for (int g = 0; g < 8; ++g) {
            union { int i; bf16x2 h2; } u;
            #pragma unroll
            for (int j = 0; j < 2; ++j) {
                float x = s[2 * g + j] * 0.125f;
                float p = (x == 0.0f) ? 0.0f : __expf(x);
                l_run += p;
                u.h2[j] = (bf16_t)p;
            }
            q8[g] = u.i;
        }

        // O^T += V^T P^T : A = Vt-frag (swizzled LDS), B = P^T-frag via half-wave exchange
        #pragma unroll
        for (int s2 = 0; s2 < 2; ++s2) {
            int r0 = __shfl_xor(q8[4 * s2 + 0], 32);
            int r1 = __shfl_xor(q8[4 * s2 + 1], 32);
            int r2 = __shfl_xor(q8[4 * s2 + 2], 32);
            int r3 = __shfl_xor(q8[4 * s2 + 3], 32);
            union { int i4[4]; bf16x8 v; } bf;
            bf.i4[0] = h ? r2 : q8[4 * s2 + 0];
            bf.i4[1] = h ? r3 : q8[4 * s2 + 1];
            bf.i4[2] = h ? q8[4 * s2 + 2] : r0;
            bf.i4[3] = h ? q8[4 * s2 + 3] : r1;
            #pragma unroll
            for (int dblk = 0; dblk < 2; ++dblk) {
                bf16x8 va = *(const bf16x8*)&lds_v[(dblk * 32 + l31) * 256 +
                                                   (((cg * 4 + s2 * 2 + h) ^ sw) << 3)];
                o_acc[dblk] = __builtin_amdgcn_mfma_f32_32x32x16_bf16(va, bf.v, o_acc[dblk], 0, 0, 0);
            }
        }
    }

    __syncthreads();   // all loop LDS reads done; smem becomes o_buf / l_buf

    l_run += __shfl_xor(l_run, 32);

    if (cg > 0) {
        float* ob = o_buf + (size_t)(cg - 1) * 64 * 32;
        #pragma unroll
        for (int dblk = 0; dblk < 2; ++dblk)
            #pragma unroll
            for (int i = 0; i < 16; ++i) {
                const int d = (i & 3) + 8 * (i >> 2) + 4 * h + dblk * 32;
                ob[d * 32 + l31] = o_acc[dblk][i];
            }
        if (h == 0) l_buf[(cg - 1) * 32 + l31] = l_run;
    }
    __syncthreads();
    if (cg == 0) {
        float lsum = l_run;
        #pragma unroll
        for (int gg = 0; gg < 7; ++gg) lsum += l_buf[gg * 32 + l31];
        const float inv_l = 1.0f / lsum;
        float* op = out + ((size_t)b * N + q0 + l31) * D;
        #pragma unroll
        for (int dblk = 0; dblk < 2; ++dblk)
            #pragma unroll
            for (int g = 0; g < 4; ++g) {
                const int d0 = 8 * g + 4 * h + dblk * 32;
                floatx4 o4;
                #pragma unroll
                for (int j = 0; j < 4; ++j) {
                    float sum = o_acc[dblk][4 * g + j];
                    #pragma unroll
                    for (int gg = 0; gg < 7; ++gg)
                        sum += o_buf[(size_t)gg * 64 * 32 + (d0 + j) * 32 + l31];
                    o4[j] = sum * inv_l;
                }
                *(floatx4*)(op + d0) = o4;
            }
    }
}

extern "C" void kernel_launch(void* const* d_in, const int* in_sizes, int n_in,
                              void* d_out, int out_size, void* d_ws, size_t ws_size,
                              hipStream_t stream) {
    const float* q = (const float*)d_in[0];
    const float* k = (const float*)d_in[1];
    const float* v = (const float*)d_in[2];
    float* out = (float*)d_out;
    bf16_t* kb = (bf16_t*)d_ws;                                   // 2 MB
    bf16_t* vt = (bf16_t*)((char*)d_ws + (size_t)B * N * D * 2);  // 2 MB

    hipLaunchKernelGGL(prepass_kernel, dim3(512), dim3(256), 0, stream, k, v, kb, vt);
    hipLaunchKernelGGL(attn_kernel, dim3(512), dim3(512), 0, stream, q, kb, vt, out);
}

// Round 9
// 86.392 us; speedup vs baseline: 1.0723x; 1.0723x over previous
//
#include <hip/hip_runtime.h>
#include <hip/hip_bf16.h>

typedef __bf16 bf16_t;
typedef bf16_t bf16x2 __attribute__((ext_vector_type(2)));
typedef bf16_t bf16x4 __attribute__((ext_vector_type(4)));
typedef bf16_t bf16x8 __attribute__((ext_vector_type(8)));
typedef float  floatx4  __attribute__((ext_vector_type(4)));
typedef float  floatx16 __attribute__((ext_vector_type(16)));

constexpr int B = 8, N = 2048, D = 64;
constexpr int TSTR = 65;   // prepass transpose stride (fp32)

// --- prepass: 1-D grid, b = bx&7. bx>>8 selects K-convert / V-transpose ---
__global__ __launch_bounds__(256)
void prepass_kernel(const float* __restrict__ k, const float* __restrict__ v,
                    bf16_t* __restrict__ kb, bf16_t* __restrict__ vt) {
    __shared__ float t[64 * TSTR];
    const int tid = threadIdx.x;
    const int b   = blockIdx.x & 7;
    const int r0  = ((blockIdx.x >> 3) & 31) * 64;
    if ((blockIdx.x >> 8) == 0) {
        const float* src = k + ((size_t)b * N + r0) * D;
        bf16_t* dst = kb + ((size_t)b * N + r0) * D;
        #pragma unroll
        for (int p = 0; p < 4; ++p) {
            int e = (tid + p * 256) * 4;
            floatx4 f = *(const floatx4*)(src + e);
            bf16x4 o;
            #pragma unroll
            for (int j = 0; j < 4; ++j) o[j] = (bf16_t)f[j];
            *(bf16x4*)(dst + e) = o;
        }
    } else {
        const float* vb = v + ((size_t)b * N + r0) * D;
        #pragma unroll
        for (int p = 0; p < 4; ++p) {
            int e = (tid + p * 256) * 4;
            int row = e >> 6, col = e & 63;
            floatx4 f = *(const floatx4*)(vb + e);
            #pragma unroll
            for (int j = 0; j < 4; ++j) t[(col + j) * TSTR + row] = f[j];
        }
        __syncthreads();
        bf16_t* ob = vt + (size_t)b * D * N + r0;
        #pragma unroll
        for (int p = 0; p < 4; ++p) {
            int e = (tid + p * 256) * 4;
            int drow = e >> 6, kcol = e & 63;
            bf16x4 o;
            #pragma unroll
            for (int j = 0; j < 4; ++j) o[j] = (bf16_t)t[drow * TSTR + kcol + j];
            *(bf16x4*)(ob + (size_t)drow * N + kcol) = o;
        }
    }
}

// --- flash attention, transposed (S^T=K Q^T, O^T=V^T P^T), BM=64, BN=256 ---
// 1024 thr = 16 waves = 2 q-groups x 8 kv-slices; grid 256 = 1 block/CU,
// 4 waves/SIMD. True LDS double-buffer (2 x 64KB), ONE barrier/iter.
// Staged K/V traffic halves vs BM=32 (each block covers 2x the q rows).
__global__ __launch_bounds__(1024, 4)
void attn_kernel(const float* __restrict__ q, const bf16_t* __restrict__ kb,
                 const bf16_t* __restrict__ vt, float* __restrict__ out) {
    __shared__ char smem[131072];   // [buf][K 32KB | Vt 32KB]; post-loop: o_buf/l_buf overlay

    const int tid  = threadIdx.x;
    const int lane = tid & 63;
    const int wave = tid >> 6;
    const int qg   = wave >> 3;    // q-group: 32 q rows
    const int cg   = wave & 7;     // kv slice of 32 within the 256-tile
    const int h    = lane >> 5;
    const int l31  = lane & 31;
    const int sw   = l31 & 7;      // XOR-swizzle key for fragment reads

    const int b  = blockIdx.x & 7;
    const int q0 = (blockIdx.x >> 3) * 64 + qg * 32;

    const bf16_t* kbb = kb + (size_t)b * N * D;
    const bf16_t* vbb = vt + (size_t)b * D * N;

    // Q B-frags fp32->bf16: B[k=d][n=q=l31]
    bf16x8 qf[4];
    {
        const float* qp = q + ((size_t)b * N + q0 + l31) * D + h * 8;
        #pragma unroll
        for (int kd = 0; kd < 4; ++kd) {
            floatx4 f0 = *(const floatx4*)(qp + kd * 16);
            floatx4 f1 = *(const floatx4*)(qp + kd * 16 + 4);
            bf16x8 t;
            #pragma unroll
            for (int j = 0; j < 4; ++j) { t[j] = (bf16_t)f0[j]; t[j + 4] = (bf16_t)f1[j]; }
            qf[kd] = t;
        }
    }

    floatx16 o_acc[2];
    #pragma unroll
    for (int d = 0; d < 2; ++d)
        #pragma unroll
        for (int i = 0; i < 16; ++i) o_acc[d][i] = 0.f;
    float l_run = 0.f;

    // preload tile 0 (1024 threads: 2 granules each for K and V)
    bf16x8 kreg[2], vreg[2];
    #pragma unroll
    for (int p = 0; p < 2; ++p) {
        int e = (tid + p * 1024) * 8;                  // 0..16383 of a 256x64 tile
        kreg[p] = *(const bf16x8*)(kbb + e);
        vreg[p] = *(const bf16x8*)(vbb + (size_t)(e >> 8) * N + (e & 255));
    }

    #pragma unroll 1
    for (int it = 0; it < N / 256; ++it) {
        char* base = smem + (it & 1) * 65536;
        bf16_t* lds_k = (bf16_t*)base;                 // [256][64] swizzled
        bf16_t* lds_v = (bf16_t*)(base + 32768);       // [64][256] swizzled

        // stage prefetched regs -> this iter's buffer (swizzled)
        #pragma unroll
        for (int p = 0; p < 2; ++p) {
            int e  = (tid + p * 1024) * 8;
            int kr = e >> 6, kg = (e >> 3) & 7;
            *(bf16x8*)&lds_k[kr * 64 + ((kg ^ (kr & 7)) << 3)] = kreg[p];
            int vr = e >> 8, vg = (e >> 3) & 31;
            *(bf16x8*)&lds_v[vr * 256 + ((vg ^ (vr & 7)) << 3)] = vreg[p];
        }
        __syncthreads();   // single barrier: buf^1 reuse distance is 2 iters (safe)

        // prefetch next tile into regs (in flight during compute)
        if (it + 1 < N / 256) {
            const int kv1 = (it + 1) * 256;
            #pragma unroll
            for (int p = 0; p < 2; ++p) {
                int e = (tid + p * 1024) * 8;
                kreg[p] = *(const bf16x8*)(kbb + (size_t)kv1 * D + e);
                vreg[p] = *(const bf16x8*)(vbb + (size_t)(e >> 8) * N + kv1 + (e & 255));
            }
        }

        // S^T = K Q^T (32kv x 32q)
        floatx16 s;
        #pragma unroll
        for (int i = 0; i < 16; ++i) s[i] = 0.f;
        #pragma unroll
        for (int kd = 0; kd < 4; ++kd) {
            bf16x8 kf = *(const bf16x8*)&lds_k[(cg * 32 + l31) * 64 + (((2 * kd + h) ^ sw) << 3)];
            s = __builtin_amdgcn_mfma_f32_32x32x16_bf16(kf, qf[kd], s, 0, 0, 0);
        }

        // scale + equality-mask (attn==0 -> -inf -> weight 0) + exp; pack bf16 pairs
        int q8[8];
        #pragma unroll
        for (int g = 0; g < 8; ++g) {
            union { int i; bf16x2 h2; } u;
            #pragma unroll
            for (int j = 0; j < 2; ++j) {
                float x = s[2 * g + j] * 0.125f;
                float p = (x == 0.0f) ? 0.0f : __expf(x);
                l_run += p;
                u.h2[j] = (bf16_t)p;
            }
            q8[g] = u.i;
        }

        // O^T += V^T P^T : A = Vt-frag (swizzled LDS), B = P^T-frag via half-wave exchange
        #pragma unroll
        for (int s2 = 0; s2 < 2; ++s2) {
            int r0 = __shfl_xor(q8[4 * s2 + 0], 32);
            int r1 = __shfl_xor(q8[4 * s2 + 1], 32);
            int r2 = __shfl_xor(q8[4 * s2 + 2], 32);
            int r3 = __shfl_xor(q8[4 * s2 + 3], 32);
            union { int i4[4]; bf16x8 v; } bf;
            bf.i4[0] = h ? r2 : q8[4 * s2 + 0];
            bf.i4[1] = h ? r3 : q8[4 * s2 + 1];
            bf.i4[2] = h ? q8[4 * s2 + 2] : r0;
            bf.i4[3] = h ? q8[4 * s2 + 3] : r1;
            #pragma unroll
            for (int dblk = 0; dblk < 2; ++dblk) {
                bf16x8 va = *(const bf16x8*)&lds_v[(dblk * 32 + l31) * 256 +
                                                   (((cg * 4 + s2 * 2 + h) ^ sw) << 3)];
                o_acc[dblk] = __builtin_amdgcn_mfma_f32_32x32x16_bf16(va, bf.v, o_acc[dblk], 0, 0, 0);
            }
        }
    }

    __syncthreads();   // all loop LDS reads done; smem becomes o_buf / l_buf

    // complete this lane's denom (partner half-wave holds the other 16 kv rows)
    l_run += __shfl_xor(l_run, 32);

    // per-q-group merge of the 8 kv-slice partials
    // o_buf: [qg][7][64][32] fp32 = 2 x 57344 B; l_buf: [qg][7][32] at +114688
    if (cg > 0) {
        float* ob = (float*)smem + (size_t)qg * 14336 + (size_t)(cg - 1) * 2048;
        #pragma unroll
        for (int dblk = 0; dblk < 2; ++dblk)
            #pragma unroll
            for (int i = 0; i < 16; ++i) {
                const int d = (i & 3) + 8 * (i >> 2) + 4 * h + dblk * 32;
                ob[d * 32 + l31] = o_acc[dblk][i];
            }
        if (h == 0) ((float*)(smem + 114688))[qg * 224 + (cg - 1) * 32 + l31] = l_run;
    }
    __syncthreads();
    if (cg == 0) {
        const float* lb = (const float*)(smem + 114688) + qg * 224;
        float lsum = l_run;
        #pragma unroll
        for (int gg = 0; gg < 7; ++gg) lsum += lb[gg * 32 + l31];
        const float inv_l = 1.0f / lsum;
        const float* ob = (const float*)smem + (size_t)qg * 14336;
        float* op = out + ((size_t)b * N + q0 + l31) * D;
        #pragma unroll
        for (int dblk = 0; dblk < 2; ++dblk)
            #pragma unroll
            for (int g = 0; g < 4; ++g) {
                const int d0 = 8 * g + 4 * h + dblk * 32;
                floatx4 o4;
                #pragma unroll
                for (int j = 0; j < 4; ++j) {
                    float sum = o_acc[dblk][4 * g + j];
                    #pragma unroll
                    for (int gg = 0; gg < 7; ++gg)
                        sum += ob[gg * 2048 + (d0 + j) * 32 + l31];
                    o4[j] = sum * inv_l;
                }
                *(floatx4*)(op + d0) = o4;
            }
    }
}

extern "C" void kernel_launch(void* const* d_in, const int* in_sizes, int n_in,
                              void* d_out, int out_size, void* d_ws, size_t ws_size,
                              hipStream_t stream) {
    const float* q = (const float*)d_in[0];
    const float* k = (const float*)d_in[1];
    const float* v = (const float*)d_in[2];
    float* out = (float*)d_out;
    bf16_t* kb = (bf16_t*)d_ws;                                   // 2 MB
    bf16_t* vt = (bf16_t*)((char*)d_ws + (size_t)B * N * D * 2);  // 2 MB

    hipLaunchKernelGGL(prepass_kernel, dim3(512), dim3(256), 0, stream, k, v, kb, vt);
    hipLaunchKernelGGL(attn_kernel, dim3(256), dim3(1024), 0, stream, q, kb, vt, out);
}